// Round 12
// baseline (34.454 us; speedup 1.0000x reference)
//
#include <hip/hip_runtime.h>
#include <hip/hip_bf16.h>

// Problem constants
#define BB 32   // batch
#define NN 512  // ragged items (reduced axis)
#define SS 32   // static input size (rows per token tile)
#define WW 64   // attention layer width (K of GEMM1, also hidden width)
#define PP 64   // layer param (output features)

#define NCHUNK 16              // n's per block
#define CHB    (NN / NCHUNK)   // 32 chunks per b
#define TPW    8               // tokens per wave (2 waves per block)

typedef __attribute__((ext_vector_type(8))) short bf16x8;  // 8 bf16 (4 VGPRs)
typedef __attribute__((ext_vector_type(8))) short short8;
typedef __attribute__((ext_vector_type(4))) float f32x4;   // MFMA acc / vec loads

typedef __attribute__((address_space(1))) const void* as1cv;
typedef __attribute__((address_space(3))) void* as3v;

// f32 -> bf16 via native cast; compiler emits v_cvt_pk_bf16_f32 pairs
__device__ __forceinline__ short f2bf(float v) {
    __hip_bfloat16 h = __float2bfloat16(v);
    return __builtin_bit_cast(short, h);
}
__device__ __forceinline__ float bf2f(unsigned short u) {
    return __builtin_bit_cast(float, ((unsigned)u) << 16);
}

// Kernel 1: h-partials for chunk c of batch b:
//   part[b][s][c][w] = bf16( sum_{n in chunk} relu(x[b,n,s,:] @ W1[:,w] + b1[w]) )
// 1024 blocks x 128 threads (2 waves), 8 tokens/wave; per-wave private LDS
// double buffer filled by global_load_lds (16B/lane, linear contiguous 1KB
// wave spans), counted vmcnt(8) waits. vs R11: 2 waves/block -> 32 KiB LDS ->
// 5 blocks/CU (10 waves/CU), so one block's prologue/epilogue overlaps four
// other blocks' streaming instead of one. Per-wave schedule unchanged.
__global__ __launch_bounds__(128) void pool1(const float* __restrict__ x,
                                             const float* __restrict__ W1,
                                             const float* __restrict__ b1,
                                             unsigned short* __restrict__ part) {
    __shared__ float stg[2][2][2048];   // 32 KiB: [wave][dbuf][8KB token image]

    const int tid  = threadIdx.x;
    const int wv   = tid >> 6;        // wave 0..1
    const int lane = tid & 63;
    const int g    = lane >> 4;       // lane group 0..3
    const int q    = lane & 15;
    const int b     = blockIdx.x >> 5;   // CHB == 32
    const int chunk = blockIdx.x & 31;

    const float* tok0 = x + ((size_t)(b * NN + chunk * NCHUNK + wv * TPW)) * (SS * WW);

    // stage token t into stg[wv][dbuf]: 8 x global_load_lds, each one
    // contiguous 1KB wave request (lane L -> bytes [k*1024 + L*16, +16))
    auto STAGE = [&](int dbuf, int t) {
        const float* tbase = tok0 + (size_t)t * (SS * WW);
#pragma unroll
        for (int k = 0; k < 8; ++k) {
            const float* src = tbase + k * 256 + lane * 4;
            __builtin_amdgcn_global_load_lds((as1cv)src, (as3v)&stg[wv][dbuf][k * 256],
                                             16, 0, 0);
        }
    };

    // issue the first two token stages FIRST — x streaming starts immediately
    STAGE(0, 0);
    STAGE(1, 1);

    // W1 fragments (B operand): wfrag[nt][ks] elem j = W1[ks*32+g*8+j][nt*16+q]
    bf16x8 wfrag[4][2];
#pragma unroll
    for (int nt = 0; nt < 4; ++nt) {
#pragma unroll
        for (int ks = 0; ks < 2; ++ks) {
            bf16x8 f;
#pragma unroll
            for (int j = 0; j < 8; ++j)
                f[j] = f2bf(W1[(ks * 32 + g * 8 + j) * WW + nt * 16 + q]);
            wfrag[nt][ks] = f;
        }
    }

    // bias for D col = nt*16+q (same for all 4 acc regs)
    float bias[4];
#pragma unroll
    for (int nt = 0; nt < 4; ++nt) bias[nt] = b1[nt * 16 + q];
    // force bias materialized here (no compiler-deferred vmem wait inside loop)
#pragma unroll
    for (int nt = 0; nt < 4; ++nt) asm volatile("" : "+v"(bias[nt]));

    f32x4 hrun[2][4];
#pragma unroll
    for (int mt = 0; mt < 2; ++mt)
#pragma unroll
        for (int nt = 0; nt < 4; ++nt)
            hrun[mt][nt] = (f32x4){0.f, 0.f, 0.f, 0.f};

    // prologue landed: W1/bias in regs, tok0/tok1 in LDS; counter now 0
    asm volatile("s_waitcnt vmcnt(0)" ::: "memory");
    __builtin_amdgcn_sched_barrier(0);

    // consume one staged token: fragment-gather ds_read_b128, cvt, 8 MFMA, relu-acc
    auto COMPUTE = [&](int dbuf) {
        const char* base = (const char*)&stg[wv][dbuf][0];
        bf16x8 afrag[2][2];
#pragma unroll
        for (int mt = 0; mt < 2; ++mt) {
#pragma unroll
            for (int ks = 0; ks < 2; ++ks) {
                // afrag elem j = x[row = mt*16+q][col = ks*32 + g*8 + j]
                const unsigned o = (unsigned)((mt * 16 + q) * 256 + ks * 128 + g * 32);
                f32x4 lo = *reinterpret_cast<const f32x4*>(base + o);
                f32x4 hi = *reinterpret_cast<const f32x4*>(base + o + 16);
                bf16x8 f;
                f[0] = f2bf(lo[0]); f[1] = f2bf(lo[1]); f[2] = f2bf(lo[2]); f[3] = f2bf(lo[3]);
                f[4] = f2bf(hi[0]); f[5] = f2bf(hi[1]); f[6] = f2bf(hi[2]); f[7] = f2bf(hi[3]);
                afrag[mt][ks] = f;
            }
        }
#pragma unroll
        for (int mt = 0; mt < 2; ++mt) {
#pragma unroll
            for (int nt = 0; nt < 4; ++nt) {
                float bv = bias[nt];
                f32x4 acc = (f32x4){bv, bv, bv, bv};
                acc = __builtin_amdgcn_mfma_f32_16x16x32_bf16(afrag[mt][0], wfrag[nt][0], acc, 0, 0, 0);
                acc = __builtin_amdgcn_mfma_f32_16x16x32_bf16(afrag[mt][1], wfrag[nt][1], acc, 0, 0, 0);
#pragma unroll
                for (int r = 0; r < 4; ++r)
                    hrun[mt][nt][r] += fmaxf(acc[r], 0.f);
            }
        }
    };

    // 8-token ping-pong; tok0/tok1 already drained by the prologue vmcnt(0)
#pragma unroll
    for (int t = 0; t < TPW; ++t) {
        if (t == TPW - 1) { asm volatile("s_waitcnt vmcnt(0)" ::: "memory"); }
        else if (t >= 2)  { asm volatile("s_waitcnt vmcnt(8)" ::: "memory"); }
        __builtin_amdgcn_sched_barrier(0);
        COMPUTE(t & 1);
        if (t < TPW - 2) STAGE(t & 1, t + 2);
    }

    // cross-wave reduce: reuse stg[wv][0] (8KB/wave) as the reduce buffer
    float* red = &stg[wv][0][0];
#pragma unroll
    for (int mt = 0; mt < 2; ++mt)
#pragma unroll
        for (int nt = 0; nt < 4; ++nt)
#pragma unroll
            for (int r = 0; r < 4; ++r)
                red[(mt * 16 + g * 4 + r) * WW + nt * 16 + q] = hrun[mt][nt][r];
    __syncthreads();

    // pack to bf16 and store: thread -> (s_row = tid>>2, 16-w span = (tid&3)*16)
    // dst layout [b][s][c][w]: pool2 then reads a contiguous 4KB per row.
    {
        const int s_row = tid >> 2;         // 0..31
        const int w0    = (tid & 3) * 16;   // 0,16,32,48
        unsigned short* dst = part + ((((size_t)b * SS + s_row) * CHB) + chunk) * WW + w0;
#pragma unroll
        for (int h8 = 0; h8 < 2; ++h8) {
            const int w = w0 + h8 * 8;
            f32x4 a0 = *reinterpret_cast<const f32x4*>(&stg[0][0][s_row * WW + w]);
            f32x4 a1 = *reinterpret_cast<const f32x4*>(&stg[1][0][s_row * WW + w]);
            f32x4 c0 = *reinterpret_cast<const f32x4*>(&stg[0][0][s_row * WW + w + 4]);
            f32x4 c1 = *reinterpret_cast<const f32x4*>(&stg[1][0][s_row * WW + w + 4]);
            f32x4 sa = a0 + a1;
            f32x4 sb = c0 + c1;
            short8 pk;
            pk[0] = f2bf(sa[0]); pk[1] = f2bf(sa[1]); pk[2] = f2bf(sa[2]); pk[3] = f2bf(sa[3]);
            pk[4] = f2bf(sb[0]); pk[5] = f2bf(sb[1]); pk[6] = f2bf(sb[2]); pk[7] = f2bf(sb[3]);
            *reinterpret_cast<short8*>(dst + h8 * 8) = pk;
        }
    }
}

// Kernel 2: out[b,s,p] = sum_w (sum_c part[b][s][c][w]) * W2[w,p] + NN * b2[p]
// 1024 blocks (one per output row); the row's 32x64 bf16 tile is contiguous
// (4KB). 4 waves split the 32-chunk reduction, wave 0 does the 64x64 matvec.
__global__ __launch_bounds__(256) void pool2(const unsigned short* __restrict__ part,
                                             const float* __restrict__ W2,
                                             const float* __restrict__ b2,
                                             float* __restrict__ out) {
    const int tid  = threadIdx.x;
    const int wv   = tid >> 6;
    const int lane = tid & 63;
    const int row  = blockIdx.x;        // b*SS + s

    const unsigned short* pb = part + (size_t)row * (CHB * WW) + lane;
    float h = 0.f;
#pragma unroll
    for (int c = 0; c < CHB / 4; ++c)
        h += bf2f(pb[(wv * (CHB / 4) + c) * WW]);

    __shared__ float hs[4][WW];
    hs[wv][lane] = h;
    __syncthreads();

    if (wv == 0) {
        float acc = (float)NN * b2[lane];
#pragma unroll
        for (int w = 0; w < WW; ++w) {
            float hw = (hs[0][w] + hs[1][w]) + (hs[2][w] + hs[3][w]);
            acc = fmaf(hw, W2[w * PP + lane], acc);
        }
        out[row * PP + lane] = acc;
    }
}

extern "C" void kernel_launch(void* const* d_in, const int* in_sizes, int n_in,
                              void* d_out, int out_size, void* d_ws, size_t ws_size,
                              hipStream_t stream) {
    const float* x  = (const float*)d_in[0];
    const float* W1 = (const float*)d_in[1];
    const float* b1 = (const float*)d_in[2];
    const float* W2 = (const float*)d_in[3];
    const float* b2 = (const float*)d_in[4];
    float* out = (float*)d_out;
    unsigned short* part = (unsigned short*)d_ws;  // [b][s][c][w] bf16 = 4 MiB

    pool1<<<dim3(BB * CHB), dim3(128), 0, stream>>>(x, W1, b1, part);
    pool2<<<dim3(BB * SS), dim3(256), 0, stream>>>(part, W2, b2, out);
}

// Round 13
// 32.343 us; speedup vs baseline: 1.0653x; 1.0653x over previous
//
#include <hip/hip_runtime.h>
#include <hip/hip_bf16.h>

// Problem constants
#define BB 32   // batch
#define NN 512  // ragged items (reduced axis)
#define SS 32   // static input size (rows per token tile)
#define WW 64   // attention layer width (K of GEMM1, also hidden width)
#define PP 64   // layer param (output features)

#define NCHUNK 16              // n's per block (4 tokens per wave)
#define CHB    (NN / NCHUNK)   // 32 chunks per b

typedef __attribute__((ext_vector_type(8))) short bf16x8;  // 8 bf16 (4 VGPRs)
typedef __attribute__((ext_vector_type(8))) short short8;
typedef __attribute__((ext_vector_type(4))) float f32x4;   // MFMA acc / vec loads

// f32 -> bf16 via native cast; compiler emits v_cvt_pk_bf16_f32 pairs
__device__ __forceinline__ short f2bf(float v) {
    __hip_bfloat16 h = __float2bfloat16(v);
    return __builtin_bit_cast(short, h);
}
__device__ __forceinline__ float bf2f(unsigned short u) {
    return __builtin_bit_cast(float, ((unsigned)u) << 16);
}

// per-token register tile: 8 x f32x4 = the lane's exact MFMA fragment bytes
struct Tok { f32x4 v[8]; };   // k = mt*4 + ks*2 + half

// Kernel 1: h-partials for chunk c of batch b:
//   part[b][s][c][w] = bf16( sum_{n in chunk} relu(x[b,n,s,:] @ W1[:,w] + b1[w]) )
// 1024 blocks x 256 threads (4 waves), 4 tokens/wave. DIRECT global->register
// loads (no LDS staging at all): each lane loads its 8 fragment granules per
// token, double-buffered 2 tokens deep in registers; compiler schedules the
// vmcnt pipeline. LDS holds only the 32KB cross-wave reduce buffer; ~140 VGPR
// -> ~3 waves/SIMD (12 waves/CU), 1.5x the LDS-path parallelism.
__global__ __launch_bounds__(256) void pool1(const float* __restrict__ x,
                                             const float* __restrict__ W1,
                                             const float* __restrict__ b1,
                                             unsigned short* __restrict__ part) {
    __shared__ float red[4][SS * WW];   // 32 KiB reduce buffer

    const int tid  = threadIdx.x;
    const int wv   = tid >> 6;
    const int lane = tid & 63;
    const int g    = lane >> 4;       // lane group 0..3
    const int q    = lane & 15;
    const int b     = blockIdx.x >> 5;   // CHB == 32
    const int chunk = blockIdx.x & 31;

    const float* tok0 = x + ((size_t)(b * NN + chunk * NCHUNK + wv * 4)) * (SS * WW);

    // load token t's fragment granules straight into registers
    auto LOADTOK = [&](Tok& T, int t) {
        const float* tb = tok0 + (size_t)t * (SS * WW);
#pragma unroll
        for (int k = 0; k < 8; ++k) {
            const int mt = k >> 2, ks = (k >> 1) & 1, half = k & 1;
            T.v[k] = *reinterpret_cast<const f32x4*>(
                tb + (mt * 16 + q) * WW + ks * 32 + g * 8 + half * 4);
        }
    };

    // x streaming starts immediately; W1 latency hides under it
    Tok A, B;
    LOADTOK(A, 0);
    LOADTOK(B, 1);

    // W1 fragments (B operand): wfrag[nt][ks] elem j = W1[ks*32+g*8+j][nt*16+q]
    bf16x8 wfrag[4][2];
#pragma unroll
    for (int nt = 0; nt < 4; ++nt) {
#pragma unroll
        for (int ks = 0; ks < 2; ++ks) {
            bf16x8 f;
#pragma unroll
            for (int j = 0; j < 8; ++j)
                f[j] = f2bf(W1[(ks * 32 + g * 8 + j) * WW + nt * 16 + q]);
            wfrag[nt][ks] = f;
        }
    }

    // bias for D col = nt*16+q (same for all 4 acc regs)
    float bias[4];
#pragma unroll
    for (int nt = 0; nt < 4; ++nt) bias[nt] = b1[nt * 16 + q];

    f32x4 hrun[2][4];
#pragma unroll
    for (int mt = 0; mt < 2; ++mt)
#pragma unroll
        for (int nt = 0; nt < 4; ++nt)
            hrun[mt][nt] = (f32x4){0.f, 0.f, 0.f, 0.f};

    // consume one register-resident token: cvt, 8 MFMA, relu-acc
    auto COMPUTE = [&](const Tok& T) {
        bf16x8 afrag[2][2];
#pragma unroll
        for (int mt = 0; mt < 2; ++mt) {
#pragma unroll
            for (int ks = 0; ks < 2; ++ks) {
                f32x4 lo = T.v[mt * 4 + ks * 2 + 0];
                f32x4 hi = T.v[mt * 4 + ks * 2 + 1];
                bf16x8 f;
                f[0] = f2bf(lo[0]); f[1] = f2bf(lo[1]); f[2] = f2bf(lo[2]); f[3] = f2bf(lo[3]);
                f[4] = f2bf(hi[0]); f[5] = f2bf(hi[1]); f[6] = f2bf(hi[2]); f[7] = f2bf(hi[3]);
                afrag[mt][ks] = f;
            }
        }
#pragma unroll
        for (int mt = 0; mt < 2; ++mt) {
#pragma unroll
            for (int nt = 0; nt < 4; ++nt) {
                float bv = bias[nt];
                f32x4 acc = (f32x4){bv, bv, bv, bv};
                acc = __builtin_amdgcn_mfma_f32_16x16x32_bf16(afrag[mt][0], wfrag[nt][0], acc, 0, 0, 0);
                acc = __builtin_amdgcn_mfma_f32_16x16x32_bf16(afrag[mt][1], wfrag[nt][1], acc, 0, 0, 0);
#pragma unroll
                for (int r = 0; r < 4; ++r)
                    hrun[mt][nt][r] += fmaxf(acc[r], 0.f);
            }
        }
    };

    // 2-deep register ping-pong over the wave's 4 tokens
    COMPUTE(A);
    LOADTOK(A, 2);
    COMPUTE(B);
    LOADTOK(B, 3);
    COMPUTE(A);
    COMPUTE(B);

    // cross-wave reduce in LDS
#pragma unroll
    for (int mt = 0; mt < 2; ++mt)
#pragma unroll
        for (int nt = 0; nt < 4; ++nt)
#pragma unroll
            for (int r = 0; r < 4; ++r)
                red[wv][(mt * 16 + g * 4 + r) * WW + nt * 16 + q] = hrun[mt][nt][r];
    __syncthreads();

    // pack to bf16 and store: thread -> (s_row = tid>>3, w-octet = tid&7)
    // dst layout [b][s][c][w]: pool2 then reads a contiguous 4KB per row.
    {
        const int s_row = tid >> 3;
        const int w0    = (tid & 7) * 8;
        f32x4 a0 = *reinterpret_cast<const f32x4*>(&red[0][s_row * WW + w0]);
        f32x4 a1 = *reinterpret_cast<const f32x4*>(&red[1][s_row * WW + w0]);
        f32x4 a2 = *reinterpret_cast<const f32x4*>(&red[2][s_row * WW + w0]);
        f32x4 a3 = *reinterpret_cast<const f32x4*>(&red[3][s_row * WW + w0]);
        f32x4 c0 = *reinterpret_cast<const f32x4*>(&red[0][s_row * WW + w0 + 4]);
        f32x4 c1 = *reinterpret_cast<const f32x4*>(&red[1][s_row * WW + w0 + 4]);
        f32x4 c2 = *reinterpret_cast<const f32x4*>(&red[2][s_row * WW + w0 + 4]);
        f32x4 c3 = *reinterpret_cast<const f32x4*>(&red[3][s_row * WW + w0 + 4]);
        f32x4 sa = (a0 + a1) + (a2 + a3);
        f32x4 sb = (c0 + c1) + (c2 + c3);
        short8 pk;
        pk[0] = f2bf(sa[0]); pk[1] = f2bf(sa[1]); pk[2] = f2bf(sa[2]); pk[3] = f2bf(sa[3]);
        pk[4] = f2bf(sb[0]); pk[5] = f2bf(sb[1]); pk[6] = f2bf(sb[2]); pk[7] = f2bf(sb[3]);
        unsigned short* dst = part + ((((size_t)b * SS + s_row) * CHB) + chunk) * WW + w0;
        *reinterpret_cast<short8*>(dst) = pk;
    }
}

// Kernel 2: out[b,s,p] = sum_w (sum_c part[b][s][c][w]) * W2[w,p] + NN * b2[p]
// 1024 blocks (one per output row); the row's 32x64 bf16 tile is contiguous
// (4KB). 4 waves split the 32-chunk reduction, wave 0 does the 64x64 matvec.
__global__ __launch_bounds__(256) void pool2(const unsigned short* __restrict__ part,
                                             const float* __restrict__ W2,
                                             const float* __restrict__ b2,
                                             float* __restrict__ out) {
    const int tid  = threadIdx.x;
    const int wv   = tid >> 6;
    const int lane = tid & 63;
    const int row  = blockIdx.x;        // b*SS + s

    const unsigned short* pb = part + (size_t)row * (CHB * WW) + lane;
    float h = 0.f;
#pragma unroll
    for (int c = 0; c < CHB / 4; ++c)
        h += bf2f(pb[(wv * (CHB / 4) + c) * WW]);

    __shared__ float hs[4][WW];
    hs[wv][lane] = h;
    __syncthreads();

    if (wv == 0) {
        float acc = (float)NN * b2[lane];
#pragma unroll
        for (int w = 0; w < WW; ++w) {
            float hw = (hs[0][w] + hs[1][w]) + (hs[2][w] + hs[3][w]);
            acc = fmaf(hw, W2[w * PP + lane], acc);
        }
        out[row * PP + lane] = acc;
    }
}

extern "C" void kernel_launch(void* const* d_in, const int* in_sizes, int n_in,
                              void* d_out, int out_size, void* d_ws, size_t ws_size,
                              hipStream_t stream) {
    const float* x  = (const float*)d_in[0];
    const float* W1 = (const float*)d_in[1];
    const float* b1 = (const float*)d_in[2];
    const float* W2 = (const float*)d_in[3];
    const float* b2 = (const float*)d_in[4];
    float* out = (float*)d_out;
    unsigned short* part = (unsigned short*)d_ws;  // [b][s][c][w] bf16 = 4 MiB

    pool1<<<dim3(BB * CHB), dim3(256), 0, stream>>>(x, W1, b1, part);
    pool2<<<dim3(BB * SS), dim3(256), 0, stream>>>(part, W2, b2, out);
}

// Round 14
// 31.335 us; speedup vs baseline: 1.0996x; 1.0322x over previous
//
#include <hip/hip_runtime.h>
#include <hip/hip_bf16.h>

// Problem constants
#define BB 32   // batch
#define NN 512  // ragged items (reduced axis)
#define SS 32   // static input size (rows per token tile)
#define WW 64   // attention layer width (K of GEMM1, also hidden width)
#define PP 64   // layer param (output features)

#define NCHUNK 16              // n's per block (4 tokens per wave)
#define CHB    (NN / NCHUNK)   // 32 chunks per b

typedef __attribute__((ext_vector_type(8))) short bf16x8;  // 8 bf16 (4 VGPRs)
typedef __attribute__((ext_vector_type(8))) short short8;
typedef __attribute__((ext_vector_type(4))) float f32x4;   // MFMA acc / vec loads

typedef __attribute__((address_space(1))) const void* as1cv;
typedef __attribute__((address_space(3))) void* as3v;

// f32 -> bf16 via native cast; compiler emits v_cvt_pk_bf16_f32 pairs
__device__ __forceinline__ short f2bf(float v) {
    __hip_bfloat16 h = __float2bfloat16(v);
    return __builtin_bit_cast(short, h);
}
__device__ __forceinline__ float bf2f(unsigned short u) {
    return __builtin_bit_cast(float, ((unsigned)u) << 16);
}

// Kernel 1: h-partials for chunk c of batch b:
//   part[b][s][c][w] = bf16( sum_{n in chunk} relu(x[b,n,s,:] @ W1[:,w] + b1[w]) )
// 1024 blocks x 256 threads (4 waves), 4 tokens/wave; per-wave private LDS
// double buffer filled by global_load_lds (16B/lane, linear contiguous 1KB
// wave spans), counted vmcnt(8) waits. The first two STAGEs issue BEFORE the
// W1/bias gather, so W1 latency hides under tok0/tok1 staging (tok loads are
// OLDER in the in-order vm counter, so the loop's counted waits remain exact;
// the post-gather vmcnt(0) = "entire prologue landed").
__global__ __launch_bounds__(256) void pool1(const float* __restrict__ x,
                                             const float* __restrict__ W1,
                                             const float* __restrict__ b1,
                                             unsigned short* __restrict__ part) {
    __shared__ float stg[4][2][2048];   // 64 KiB: [wave][dbuf][8KB token image]

    const int tid  = threadIdx.x;
    const int wv   = tid >> 6;
    const int lane = tid & 63;
    const int g    = lane >> 4;       // lane group 0..3
    const int q    = lane & 15;
    const int b     = blockIdx.x >> 5;   // CHB == 32
    const int chunk = blockIdx.x & 31;

    const float* tok0 = x + ((size_t)(b * NN + chunk * NCHUNK + wv * 4)) * (SS * WW);

    // stage token t into stg[wv][dbuf]: 8 x global_load_lds, each one
    // contiguous 1KB wave request (lane L -> bytes [k*1024 + L*16, +16))
    auto STAGE = [&](int dbuf, int t) {
        const float* tbase = tok0 + (size_t)t * (SS * WW);
#pragma unroll
        for (int k = 0; k < 8; ++k) {
            const float* src = tbase + k * 256 + lane * 4;
            __builtin_amdgcn_global_load_lds((as1cv)src, (as3v)&stg[wv][dbuf][k * 256],
                                             16, 0, 0);
        }
    };

    // issue the first two token stages FIRST — x streaming starts immediately
    STAGE(0, 0);
    STAGE(1, 1);

    // W1 fragments (B operand): wfrag[nt][ks] elem j = W1[ks*32+g*8+j][nt*16+q]
    bf16x8 wfrag[4][2];
#pragma unroll
    for (int nt = 0; nt < 4; ++nt) {
#pragma unroll
        for (int ks = 0; ks < 2; ++ks) {
            bf16x8 f;
#pragma unroll
            for (int j = 0; j < 8; ++j)
                f[j] = f2bf(W1[(ks * 32 + g * 8 + j) * WW + nt * 16 + q]);
            wfrag[nt][ks] = f;
        }
    }

    // bias for D col = nt*16+q (same for all 4 acc regs)
    float bias[4];
#pragma unroll
    for (int nt = 0; nt < 4; ++nt) bias[nt] = b1[nt * 16 + q];
    // force bias materialized here (no compiler-deferred vmem wait inside loop)
#pragma unroll
    for (int nt = 0; nt < 4; ++nt) asm volatile("" : "+v"(bias[nt]));

    f32x4 hrun[2][4];
#pragma unroll
    for (int mt = 0; mt < 2; ++mt)
#pragma unroll
        for (int nt = 0; nt < 4; ++nt)
            hrun[mt][nt] = (f32x4){0.f, 0.f, 0.f, 0.f};

    // prologue landed: W1/bias in regs, tok0/tok1 in LDS; counter now 0
    asm volatile("s_waitcnt vmcnt(0)" ::: "memory");
    __builtin_amdgcn_sched_barrier(0);

    // consume one staged token: fragment-gather ds_read_b128, cvt, 8 MFMA, relu-acc
    auto COMPUTE = [&](int dbuf) {
        const char* base = (const char*)&stg[wv][dbuf][0];
        bf16x8 afrag[2][2];
#pragma unroll
        for (int mt = 0; mt < 2; ++mt) {
#pragma unroll
            for (int ks = 0; ks < 2; ++ks) {
                // afrag elem j = x[row = mt*16+q][col = ks*32 + g*8 + j]
                const unsigned o = (unsigned)((mt * 16 + q) * 256 + ks * 128 + g * 32);
                f32x4 lo = *reinterpret_cast<const f32x4*>(base + o);
                f32x4 hi = *reinterpret_cast<const f32x4*>(base + o + 16);
                bf16x8 f;
                f[0] = f2bf(lo[0]); f[1] = f2bf(lo[1]); f[2] = f2bf(lo[2]); f[3] = f2bf(lo[3]);
                f[4] = f2bf(hi[0]); f[5] = f2bf(hi[1]); f[6] = f2bf(hi[2]); f[7] = f2bf(hi[3]);
                afrag[mt][ks] = f;
            }
        }
#pragma unroll
        for (int mt = 0; mt < 2; ++mt) {
#pragma unroll
            for (int nt = 0; nt < 4; ++nt) {
                float bv = bias[nt];
                f32x4 acc = (f32x4){bv, bv, bv, bv};
                acc = __builtin_amdgcn_mfma_f32_16x16x32_bf16(afrag[mt][0], wfrag[nt][0], acc, 0, 0, 0);
                acc = __builtin_amdgcn_mfma_f32_16x16x32_bf16(afrag[mt][1], wfrag[nt][1], acc, 0, 0, 0);
#pragma unroll
                for (int r = 0; r < 4; ++r)
                    hrun[mt][nt][r] += fmaxf(acc[r], 0.f);
            }
        }
    };

    COMPUTE(0);                                        // tok0 resident
    STAGE(0, 2);
    asm volatile("s_waitcnt vmcnt(8)" ::: "memory");   // tok1 landed (no-op-ish)
    __builtin_amdgcn_sched_barrier(0);
    COMPUTE(1);
    STAGE(1, 3);
    asm volatile("s_waitcnt vmcnt(8)" ::: "memory");   // tok2 landed
    __builtin_amdgcn_sched_barrier(0);
    COMPUTE(0);
    asm volatile("s_waitcnt vmcnt(0)" ::: "memory");   // tok3 landed
    __builtin_amdgcn_sched_barrier(0);
    COMPUTE(1);

    // cross-wave reduce: reuse stg[wv][0] (8KB/wave) as the reduce buffer
    float* red = &stg[wv][0][0];
#pragma unroll
    for (int mt = 0; mt < 2; ++mt)
#pragma unroll
        for (int nt = 0; nt < 4; ++nt)
#pragma unroll
            for (int r = 0; r < 4; ++r)
                red[(mt * 16 + g * 4 + r) * WW + nt * 16 + q] = hrun[mt][nt][r];
    __syncthreads();

    // pack to bf16 and store: thread -> (s_row = tid>>3, w-octet = tid&7)
    // dst layout [b][s][c][w]: pool2 then reads a contiguous 4KB per row.
    {
        const int s_row = tid >> 3;
        const int w0    = (tid & 7) * 8;
        f32x4 a0 = *reinterpret_cast<const f32x4*>(&stg[0][0][s_row * WW + w0]);
        f32x4 a1 = *reinterpret_cast<const f32x4*>(&stg[1][0][s_row * WW + w0]);
        f32x4 a2 = *reinterpret_cast<const f32x4*>(&stg[2][0][s_row * WW + w0]);
        f32x4 a3 = *reinterpret_cast<const f32x4*>(&stg[3][0][s_row * WW + w0]);
        f32x4 b0 = *reinterpret_cast<const f32x4*>(&stg[0][0][s_row * WW + w0 + 4]);
        f32x4 b1v = *reinterpret_cast<const f32x4*>(&stg[1][0][s_row * WW + w0 + 4]);
        f32x4 b2v = *reinterpret_cast<const f32x4*>(&stg[2][0][s_row * WW + w0 + 4]);
        f32x4 b3 = *reinterpret_cast<const f32x4*>(&stg[3][0][s_row * WW + w0 + 4]);
        f32x4 sa = (a0 + a1) + (a2 + a3);
        f32x4 sb = (b0 + b1v) + (b2v + b3);
        short8 pk;
        pk[0] = f2bf(sa[0]); pk[1] = f2bf(sa[1]); pk[2] = f2bf(sa[2]); pk[3] = f2bf(sa[3]);
        pk[4] = f2bf(sb[0]); pk[5] = f2bf(sb[1]); pk[6] = f2bf(sb[2]); pk[7] = f2bf(sb[3]);
        unsigned short* dst = part + ((((size_t)b * SS + s_row) * CHB) + chunk) * WW + w0;
        *reinterpret_cast<short8*>(dst) = pk;
    }
}

// Kernel 2: out[b,s,p] = sum_w (sum_c part[b][s][c][w]) * W2[w,p] + NN * b2[p]
// 1024 blocks (one per output row); the row's 32x64 bf16 tile is contiguous
// (4KB). 4 waves split the 32-chunk reduction, wave 0 does the 64x64 matvec.
__global__ __launch_bounds__(256) void pool2(const unsigned short* __restrict__ part,
                                             const float* __restrict__ W2,
                                             const float* __restrict__ b2,
                                             float* __restrict__ out) {
    const int tid  = threadIdx.x;
    const int wv   = tid >> 6;
    const int lane = tid & 63;
    const int row  = blockIdx.x;        // b*SS + s

    const unsigned short* pb = part + (size_t)row * (CHB * WW) + lane;
    float h = 0.f;
#pragma unroll
    for (int c = 0; c < CHB / 4; ++c)
        h += bf2f(pb[(wv * (CHB / 4) + c) * WW]);

    __shared__ float hs[4][WW];
    hs[wv][lane] = h;
    __syncthreads();

    if (wv == 0) {
        float acc = (float)NN * b2[lane];
#pragma unroll
        for (int w = 0; w < WW; ++w) {
            float hw = (hs[0][w] + hs[1][w]) + (hs[2][w] + hs[3][w]);
            acc = fmaf(hw, W2[w * PP + lane], acc);
        }
        out[row * PP + lane] = acc;
    }
}

extern "C" void kernel_launch(void* const* d_in, const int* in_sizes, int n_in,
                              void* d_out, int out_size, void* d_ws, size_t ws_size,
                              hipStream_t stream) {
    const float* x  = (const float*)d_in[0];
    const float* W1 = (const float*)d_in[1];
    const float* b1 = (const float*)d_in[2];
    const float* W2 = (const float*)d_in[3];
    const float* b2 = (const float*)d_in[4];
    float* out = (float*)d_out;
    unsigned short* part = (unsigned short*)d_ws;  // [b][s][c][w] bf16 = 4 MiB

    pool1<<<dim3(BB * CHB), dim3(256), 0, stream>>>(x, W1, b1, part);
    pool2<<<dim3(BB * SS), dim3(256), 0, stream>>>(part, W2, b2, out);
}